// Round 5
// baseline (398.466 us; speedup 1.0000x reference)
//
#include <hip/hip_runtime.h>
#include <hip/hip_bf16.h>
#include <math.h>

#define NN 40000
#define NE 640000
#define NB_SCAN 157   // ceil(NN/256)

typedef __attribute__((ext_vector_type(8))) short short8;
typedef __attribute__((ext_vector_type(8))) unsigned short u16x8;
typedef __attribute__((ext_vector_type(4))) float f32x4;

#define TS_STRIDE 88   // ushort stride for epilogue transpose tile (16B-aligned rows, 4-way max)

__device__ __forceinline__ float gelu_tanh(float x) {
    float x3 = x * x * x;
    float u = 0.7978845608028654f * (x + 0.044715f * x3);
    return 0.5f * x * (1.0f + tanhf(u));
}

__device__ __forceinline__ unsigned short f2bf(float v) {
    __hip_bfloat16 h = __float2bfloat16(v);
    return *reinterpret_cast<unsigned short*>(&h);
}

__device__ __forceinline__ float bf2f(unsigned short u) {
    union { unsigned int i; float f; } c;
    c.i = ((unsigned int)u) << 16;
    return c.f;
}

// ---------------- One-shot weight prep: fused QKV (both layers) + aW^T + fcW^T ---
// BfT[l][384][128] bf16, biasf[l][384] f32, aWT[l][128][128] bf16, fcWT[64][128] bf16
__global__ __launch_bounds__(256) void weights_kernel(
    const float* __restrict__ Wq, const float* __restrict__ bq,
    const float* __restrict__ Wk, const float* __restrict__ bk,
    const float* __restrict__ a_rel,
    const float* __restrict__ Wv, const float* __restrict__ bv,
    const float* __restrict__ m_rel,
    const float* __restrict__ p_rel,
    const float* __restrict__ aW, const float* __restrict__ fcW,
    unsigned short* __restrict__ BfT, float* __restrict__ biasf,
    unsigned short* __restrict__ aWT, unsigned short* __restrict__ fcWT)
{
    int idx = blockIdx.x * 256 + threadIdx.x;
    if (idx < 2 * 129 * 384) {
        int l = idx / (129 * 384);
        int j = idx - l * (129 * 384);
        int r = j / 384;            // 0..127 weight row (k), 128 = bias
        int col = j - r * 384;
        const float* Wq_l = Wq + l * 16384;
        const float* Wk_l = Wk + l * 16384;
        const float* Wv_l = Wv + l * 16384;
        const float* ar_l = a_rel + l * 2048;
        const float* mr_l = m_rel + l * 2048;
        float val;
        if (col < 128) {
            val = (r < 128) ? Wq_l[r * 128 + col] : bq[l * 128 + col];
        } else if (col < 256) {
            int cc = col - 128; int h = cc >> 4; int eo = cc & 15;
            float scale = p_rel[l * 8 + h] * 0.25f;
            float s = 0.f;
            #pragma unroll
            for (int d = 0; d < 16; ++d) {
                float w = (r < 128) ? Wk_l[r * 128 + h * 16 + d] : bk[l * 128 + h * 16 + d];
                s += w * ar_l[h * 256 + d * 16 + eo];
            }
            val = s * scale;
        } else {
            int cc = col - 256; int h = cc >> 4; int eo = cc & 15;
            float s = 0.f;
            #pragma unroll
            for (int d = 0; d < 16; ++d) {
                float w = (r < 128) ? Wv_l[r * 128 + h * 16 + d] : bv[l * 128 + h * 16 + d];
                s += w * mr_l[h * 256 + d * 16 + eo];
            }
            val = s;
        }
        if (r < 128) BfT[(size_t)l * 49152 + (size_t)col * 128 + r] = f2bf(val);
        else         biasf[l * 384 + col] = val;
    } else if (idx < 2 * 129 * 384 + 2 * 16384) {
        int i = idx - 2 * 129 * 384;
        int l = i >> 14; int j = i & 16383;
        int r = j >> 7, c = j & 127;
        aWT[(size_t)l * 16384 + (size_t)c * 128 + r] = f2bf(aW[(size_t)l * 16384 + r * 128 + c]);
    } else if (idx < 2 * 129 * 384 + 2 * 16384 + 8192) {
        int i = idx - (2 * 129 * 384 + 2 * 16384);
        int c = i >> 7, r = i & 127;
        fcWT[(size_t)c * 128 + r] = f2bf(fcW[(size_t)r * 64 + c]);
    }
}

// ---------------- MFMA bf16 GEMM, 64 rows x Ncols per block ----------------------
// MODE 0 (QKV):  out cols 0..127 -> qb bf16; 128..383 -> kvi interleaved bf16
// MODE 1 (agg):  gelu on A, epilogue relu(beta*(.)+(1-beta)*Hprev) -> houtB bf16
// MODE 2 (fc):   plain f32 out, Ncols=64
// AFMT: 0 = A f32 (Af), 1 = A bf16 (Ab).  HPFMT: Hprev format for MODE 1.
template <int MODE, int AFMT, int HPFMT>
__global__ __launch_bounds__(256) void mfma_gemm_kernel(
    const float* __restrict__ Af, const unsigned short* __restrict__ Ab,
    const unsigned short* __restrict__ BT, const float* __restrict__ bias,
    float* __restrict__ outF, unsigned short* __restrict__ qb,
    unsigned short* __restrict__ kvi, unsigned short* __restrict__ houtB,
    const float* __restrict__ HprevF, const unsigned short* __restrict__ HprevB,
    const float* __restrict__ skip_p, int Ncols)
{
    __shared__ unsigned short As[64][136];
    __shared__ unsigned short Bs[64][136];   // reused as epilogue transpose tile
    int t = threadIdx.x;
    int row0 = blockIdx.x * 64;
    int w = t >> 6;
    int l = t & 63;
    int lr = l & 15;
    int quad = l >> 4;

    // ---- stage A tile (64 x 128) as bf16 ----
    #pragma unroll
    for (int i = 0; i < 4; ++i) {
        int idx = t + i * 256;
        int r = idx >> 4;
        int c8 = (idx & 15) * 8;
        if (AFMT == 0) {
            float4 a0 = *(const float4*)(Af + (size_t)(row0 + r) * 128 + c8);
            float4 a1 = *(const float4*)(Af + (size_t)(row0 + r) * 128 + c8 + 4);
            ushort4 u0, u1;
            u0.x = f2bf(a0.x); u0.y = f2bf(a0.y); u0.z = f2bf(a0.z); u0.w = f2bf(a0.w);
            u1.x = f2bf(a1.x); u1.y = f2bf(a1.y); u1.z = f2bf(a1.z); u1.w = f2bf(a1.w);
            *(ushort4*)(&As[r][c8]) = u0;
            *(ushort4*)(&As[r][c8 + 4]) = u1;
        } else {
            u16x8 u = *(const u16x8*)(Ab + (size_t)(row0 + r) * 128 + c8);
            if (MODE == 1) {
                #pragma unroll
                for (int j = 0; j < 8; ++j) u[j] = f2bf(gelu_tanh(bf2f(u[j])));
            }
            *(u16x8*)(&As[r][c8]) = u;
        }
    }

    float beta = 0.f, omb = 0.f;
    if (MODE == 1) {
        float sv = skip_p[0];
        beta = 1.f / (1.f + expf(-sv));
        omb = 1.f - beta;
    }

    int nct = Ncols >> 6;
    for (int ct = 0; ct < nct; ++ct) {
        __syncthreads();   // As ready / prev epilogue reads done
        #pragma unroll
        for (int i = 0; i < 4; ++i) {
            int idx = t + i * 256;
            int r = idx >> 4;
            int c8 = (idx & 15) * 8;
            *(u16x8*)(&Bs[r][c8]) = *(const u16x8*)(BT + (size_t)(ct * 64 + r) * 128 + c8);
        }
        __syncthreads();

        f32x4 acc[4] = {{0.f,0.f,0.f,0.f},{0.f,0.f,0.f,0.f},
                        {0.f,0.f,0.f,0.f},{0.f,0.f,0.f,0.f}};
        #pragma unroll
        for (int kc = 0; kc < 4; ++kc) {
            short8 af = *(const short8*)(&As[w * 16 + lr][kc * 32 + quad * 8]);
            #pragma unroll
            for (int n4 = 0; n4 < 4; ++n4) {
                short8 bfr = *(const short8*)(&Bs[n4 * 16 + lr][kc * 32 + quad * 8]);
                acc[n4] = __builtin_amdgcn_mfma_f32_16x16x32_bf16(af, bfr, acc[n4], 0, 0, 0);
            }
        }
        __syncthreads();   // all waves done reading Bs; safe to overwrite

        // ---- write C tile (bias added) into LDS transpose buffer ----
        if (MODE == 2) {
            float* Tf = (float*)&Bs[0][0];     // stride 68 floats
            #pragma unroll
            for (int n4 = 0; n4 < 4; ++n4) {
                float bv = bias[ct * 64 + n4 * 16 + lr];
                #pragma unroll
                for (int rr = 0; rr < 4; ++rr)
                    Tf[(w * 16 + quad * 4 + rr) * 68 + n4 * 16 + lr] = acc[n4][rr] + bv;
            }
        } else {
            unsigned short* Ts = &Bs[0][0];    // stride TS_STRIDE ushorts
            #pragma unroll
            for (int n4 = 0; n4 < 4; ++n4) {
                float bv = bias[ct * 64 + n4 * 16 + lr];
                #pragma unroll
                for (int rr = 0; rr < 4; ++rr)
                    Ts[(w * 16 + quad * 4 + rr) * TS_STRIDE + n4 * 16 + lr] =
                        f2bf(acc[n4][rr] + bv);
            }
        }
        __syncthreads();

        // ---- vectorized store: thread -> (row, 16-col segment) ----
        int r = t >> 2;
        int cs = (t & 3) * 16;
        int row = row0 + r;
        if (MODE == 2) {
            float* Tf = (float*)&Bs[0][0];
            #pragma unroll
            for (int j = 0; j < 4; ++j) {
                float4 v = *(float4*)(&Tf[r * 68 + cs + j * 4]);
                *(float4*)(outF + (size_t)row * 64 + cs + j * 4) = v;
            }
        } else if (MODE == 0) {
            unsigned short* Ts = &Bs[0][0];
            u16x8 u0 = *(u16x8*)(&Ts[r * TS_STRIDE + cs]);
            u16x8 u1 = *(u16x8*)(&Ts[r * TS_STRIDE + cs + 8]);
            int col = ct * 64 + cs;
            if (col < 128) {
                *(u16x8*)(qb + (size_t)row * 128 + col) = u0;
                *(u16x8*)(qb + (size_t)row * 128 + col + 8) = u1;
            } else {
                int ch = (col - 128) & 127;
                int half = (col - 128) >> 7;
                unsigned short* P = kvi + (size_t)row * 256 + half * 2;
                int p0 = ch >> 1;
                #pragma unroll
                for (int m = 0; m < 4; ++m) {
                    ushort2 v; v.x = u0[2 * m]; v.y = u0[2 * m + 1];
                    *(ushort2*)(P + (p0 + m) * 4) = v;
                }
                #pragma unroll
                for (int m = 0; m < 4; ++m) {
                    ushort2 v; v.x = u1[2 * m]; v.y = u1[2 * m + 1];
                    *(ushort2*)(P + (p0 + 4 + m) * 4) = v;
                }
            }
        } else {  // MODE 1
            unsigned short* Ts = &Bs[0][0];
            u16x8 u0 = *(u16x8*)(&Ts[r * TS_STRIDE + cs]);
            u16x8 u1 = *(u16x8*)(&Ts[r * TS_STRIDE + cs + 8]);
            int col = ct * 64 + cs;
            float hp[16];
            if (HPFMT == 0) {
                #pragma unroll
                for (int j = 0; j < 4; ++j) {
                    float4 h4 = *(const float4*)(HprevF + (size_t)row * 128 + col + j * 4);
                    hp[j * 4 + 0] = h4.x; hp[j * 4 + 1] = h4.y;
                    hp[j * 4 + 2] = h4.z; hp[j * 4 + 3] = h4.w;
                }
            } else {
                u16x8 h0 = *(const u16x8*)(HprevB + (size_t)row * 128 + col);
                u16x8 h1 = *(const u16x8*)(HprevB + (size_t)row * 128 + col + 8);
                #pragma unroll
                for (int j = 0; j < 8; ++j) { hp[j] = bf2f(h0[j]); hp[8 + j] = bf2f(h1[j]); }
            }
            u16x8 o0, o1;
            #pragma unroll
            for (int j = 0; j < 8; ++j) {
                float v0 = fmaxf(beta * bf2f(u0[j]) + omb * hp[j], 0.f);
                float v1 = fmaxf(beta * bf2f(u1[j]) + omb * hp[8 + j], 0.f);
                o0[j] = f2bf(v0);
                o1[j] = f2bf(v1);
            }
            *(u16x8*)(houtB + (size_t)row * 128 + col) = o0;
            *(u16x8*)(houtB + (size_t)row * 128 + col + 8) = o1;
        }
    }
}

// ---------------- CSR build (once per call; both layers share structure) ---------

__global__ __launch_bounds__(256) void hist_kernel(
    const int* __restrict__ eidx, int* __restrict__ deg)
{
    int e = blockIdx.x * 256 + threadIdx.x;
    if (e < NE) atomicAdd(&deg[eidx[NE + e]], 1);
}

__global__ __launch_bounds__(256) void scan_blocks_kernel(
    const int* __restrict__ deg, int* __restrict__ offs, int* __restrict__ bsum)
{
    __shared__ int s[256];
    int t = threadIdx.x;
    int i = blockIdx.x * 256 + t;
    int v = (i < NN) ? deg[i] : 0;
    s[t] = v;
    __syncthreads();
    #pragma unroll
    for (int off = 1; off < 256; off <<= 1) {
        int u = (t >= off) ? s[t - off] : 0;
        __syncthreads();
        s[t] += u;
        __syncthreads();
    }
    if (i < NN) offs[i] = s[t] - v;
    if (t == 255) bsum[blockIdx.x] = s[255];
}

__global__ __launch_bounds__(256) void scan_top_kernel(
    const int* __restrict__ bsum, int* __restrict__ boffs)
{
    __shared__ int s[256];
    int t = threadIdx.x;
    int v = (t < NB_SCAN) ? bsum[t] : 0;
    s[t] = v;
    __syncthreads();
    #pragma unroll
    for (int off = 1; off < 256; off <<= 1) {
        int u = (t >= off) ? s[t - off] : 0;
        __syncthreads();
        s[t] += u;
        __syncthreads();
    }
    boffs[t] = s[t] - v;
}

__global__ __launch_bounds__(256) void scan_add_kernel(
    int* __restrict__ offs, const int* __restrict__ boffs, int* __restrict__ cursor)
{
    int i = blockIdx.x * 256 + threadIdx.x;
    if (i < NN) {
        int o = offs[i] + boffs[blockIdx.x];
        offs[i] = o;
        cursor[i] = o;
    }
}

__global__ __launch_bounds__(256) void scatter_kernel(
    const int* __restrict__ eidx, int* __restrict__ cursor, int* __restrict__ srcSorted)
{
    int e = blockIdx.x * 256 + threadIdx.x;
    if (e < NE) {
        int s = eidx[e];
        int d = eidx[NE + e];
        int pos = atomicAdd(&cursor[d], 1);
        srcSorted[pos] = s;
    }
}

// ---------------- Fused per-destination softmax + aggregation --------------------
__global__ __launch_bounds__(256) void aggregate_kernel(
    const unsigned short* __restrict__ qb, const unsigned short* __restrict__ kvi,
    const int* __restrict__ deg, const int* __restrict__ offs,
    const int* __restrict__ srcSorted, unsigned short* __restrict__ aggb)
{
    int wid = (blockIdx.x * 256 + threadIdx.x) >> 6;
    int lane = threadIdx.x & 63;
    int n = wid;
    ushort2 qu = *(const ushort2*)(qb + (size_t)n * 128 + 2 * lane);
    float qx = bf2f(qu.x), qy = bf2f(qu.y);
    int start = offs[n];
    int d = deg[n];
    float accx = 0.f, accy = 0.f, den = 0.f;

    int s_cur = (d > 0) ? srcSorted[start] : 0;
    int s_next = (d > 1) ? srcSorted[start + 1] : 0;
    ushort4 kv_cur = *(const ushort4*)(kvi + (size_t)s_cur * 256 + lane * 4);

    for (int j = 0; j < d; ++j) {
        int s_nn = (j + 2 < d) ? srcSorted[start + j + 2] : 0;
        ushort4 kv_next = *(const ushort4*)(kvi + (size_t)s_next * 256 + lane * 4);
        float kx = bf2f(kv_cur.x), ky = bf2f(kv_cur.y);
        float vx = bf2f(kv_cur.z), vy = bf2f(kv_cur.w);
        float p = qx * kx + qy * ky;
        p += __shfl_xor(p, 1, 8);
        p += __shfl_xor(p, 2, 8);
        p += __shfl_xor(p, 4, 8);
        float ev = expf(p);
        den += ev;
        accx += vx * ev;
        accy += vy * ev;
        kv_cur = kv_next;
        s_next = s_nn;
    }
    float w = 1.0f / (den + 1e-16f);
    ushort2 o;
    o.x = f2bf(accx * w);
    o.y = f2bf(accy * w);
    *(ushort2*)(aggb + (size_t)n * 128 + 2 * lane) = o;
}

extern "C" void kernel_launch(void* const* d_in, const int* in_sizes, int n_in,
                              void* d_out, int out_size, void* d_ws, size_t ws_size,
                              hipStream_t stream) {
    const float* x     = (const float*)d_in[0];
    const int*   eidx  = (const int*)d_in[1];
    const float* Wk    = (const float*)d_in[2];
    const float* bk    = (const float*)d_in[3];
    const float* Wq    = (const float*)d_in[4];
    const float* bq    = (const float*)d_in[5];
    const float* Wv    = (const float*)d_in[6];
    const float* bv    = (const float*)d_in[7];
    const float* a_rel = (const float*)d_in[8];
    const float* m_rel = (const float*)d_in[9];
    const float* p_rel = (const float*)d_in[10];
    const float* skip  = (const float*)d_in[11];
    const float* aW    = (const float*)d_in[12];
    const float* ab    = (const float*)d_in[13];
    const float* fcW   = (const float*)d_in[14];
    const float* fcb   = (const float*)d_in[15];
    float* out = (float*)d_out;

    float* biasf = (float*)d_ws;                              // 2*384
    unsigned short* hb   = (unsigned short*)(biasf + 768);    // NN*128
    unsigned short* qb   = hb + (size_t)NN * 128;             // NN*128
    unsigned short* kvi  = qb + (size_t)NN * 128;             // NN*256
    unsigned short* aggb = kvi + (size_t)NN * 256;            // NN*128
    unsigned short* BfT  = aggb + (size_t)NN * 128;           // 2*384*128
    unsigned short* aWT  = BfT + 2 * 384 * 128;               // 2*128*128
    unsigned short* fcWT = aWT + 2 * 128 * 128;               // 64*128
    int* deg       = (int*)(fcWT + 64 * 128);                 // NN
    int* offs      = deg + NN;
    int* cursor    = offs + NN;
    int* bsum      = cursor + NN;                             // 256
    int* boffs     = bsum + 256;                              // 256
    int* srcSorted = boffs + 256;                             // NE

    // ---- weight prep (both layers + fc), one launch ----
    weights_kernel<<<547, 256, 0, stream>>>(
        Wq, bq, Wk, bk, a_rel, Wv, bv, m_rel, p_rel, aW, fcW,
        BfT, biasf, aWT, fcWT);

    // ---- CSR build ----
    hipMemsetAsync(deg, 0, (size_t)NN * sizeof(int), stream);
    hist_kernel<<<(NE + 255) / 256, 256, 0, stream>>>(eidx, deg);
    scan_blocks_kernel<<<NB_SCAN, 256, 0, stream>>>(deg, offs, bsum);
    scan_top_kernel<<<1, 256, 0, stream>>>(bsum, boffs);
    scan_add_kernel<<<NB_SCAN, 256, 0, stream>>>(offs, boffs, cursor);
    scatter_kernel<<<(NE + 255) / 256, 256, 0, stream>>>(eidx, cursor, srcSorted);

    // ---- layer 0 ----
    mfma_gemm_kernel<0, 0, 0><<<625, 256, 0, stream>>>(
        x, nullptr, BfT, biasf, nullptr, qb, kvi, nullptr, nullptr, nullptr, nullptr, 384);
    aggregate_kernel<<<NN / 4, 256, 0, stream>>>(qb, kvi, deg, offs, srcSorted, aggb);
    mfma_gemm_kernel<1, 1, 0><<<625, 256, 0, stream>>>(
        nullptr, aggb, aWT, ab, nullptr, nullptr, nullptr, hb, x, nullptr, skip, 128);

    // ---- layer 1 ----
    mfma_gemm_kernel<0, 1, 0><<<625, 256, 0, stream>>>(
        nullptr, hb, BfT + 49152, biasf + 384, nullptr, qb, kvi, nullptr, nullptr, nullptr, nullptr, 384);
    aggregate_kernel<<<NN / 4, 256, 0, stream>>>(qb, kvi, deg, offs, srcSorted, aggb);
    mfma_gemm_kernel<1, 1, 1><<<625, 256, 0, stream>>>(
        nullptr, aggb, aWT + 16384, ab + 128, nullptr, nullptr, nullptr, hb, nullptr, hb, skip + 1, 128);

    // ---- final fc ----
    mfma_gemm_kernel<2, 1, 0><<<625, 256, 0, stream>>>(
        nullptr, hb, fcWT, fcb, out, nullptr, nullptr, nullptr, nullptr, nullptr, nullptr, 64);
}

// Round 6
// 320.281 us; speedup vs baseline: 1.2441x; 1.2441x over previous
//
#include <hip/hip_runtime.h>
#include <hip/hip_bf16.h>
#include <math.h>

#define NN 40000
#define NE 640000
#define NB_SCAN 157   // ceil(NN/256)

typedef __attribute__((ext_vector_type(8))) short short8;
typedef __attribute__((ext_vector_type(8))) unsigned short u16x8;
typedef __attribute__((ext_vector_type(4))) float f32x4;

__device__ __forceinline__ float gelu_tanh(float x) {
    float x3 = x * x * x;
    float u = 0.7978845608028654f * (x + 0.044715f * x3);
    return 0.5f * x * (1.0f + tanhf(u));
}

__device__ __forceinline__ unsigned short f2bf(float v) {
    __hip_bfloat16 h = __float2bfloat16(v);
    return *reinterpret_cast<unsigned short*>(&h);
}

__device__ __forceinline__ float bf2f(unsigned short u) {
    union { unsigned int i; float f; } c;
    c.i = ((unsigned int)u) << 16;
    return c.f;
}

// unpack 8 bf16 (one u16x8) -> 8 f32 using dword mask/shift (2 ops per pair)
__device__ __forceinline__ void unpack8(u16x8 u, float* f) {
    union { u16x8 v; unsigned int d[4]; } c; c.v = u;
    #pragma unroll
    for (int i = 0; i < 4; ++i) {
        union { unsigned int i_; float f_; } lo, hi;
        lo.i_ = c.d[i] << 16;
        hi.i_ = c.d[i] & 0xffff0000u;
        f[2 * i] = lo.f_;
        f[2 * i + 1] = hi.f_;
    }
}

// ---------------- One-shot weight prep: fused QKV (both layers) + aW^T + fcW^T ---
// BfT[l][384][128] bf16, biasf[l][384] f32, aWT[l][128][128] bf16, fcWT[64][128] bf16
// k-section (cols 128..255) folds p_rel * 1/sqrt(16) * log2(e)  (softmax via exp2)
__global__ __launch_bounds__(256) void weights_kernel(
    const float* __restrict__ Wq, const float* __restrict__ bq,
    const float* __restrict__ Wk, const float* __restrict__ bk,
    const float* __restrict__ a_rel,
    const float* __restrict__ Wv, const float* __restrict__ bv,
    const float* __restrict__ m_rel,
    const float* __restrict__ p_rel,
    const float* __restrict__ aW, const float* __restrict__ fcW,
    unsigned short* __restrict__ BfT, float* __restrict__ biasf,
    unsigned short* __restrict__ aWT, unsigned short* __restrict__ fcWT)
{
    int idx = blockIdx.x * 256 + threadIdx.x;
    if (idx < 2 * 129 * 384) {
        int l = idx / (129 * 384);
        int j = idx - l * (129 * 384);
        int r = j / 384;            // 0..127 weight row (k), 128 = bias
        int col = j - r * 384;
        const float* Wq_l = Wq + l * 16384;
        const float* Wk_l = Wk + l * 16384;
        const float* Wv_l = Wv + l * 16384;
        const float* ar_l = a_rel + l * 2048;
        const float* mr_l = m_rel + l * 2048;
        float val;
        if (col < 128) {
            val = (r < 128) ? Wq_l[r * 128 + col] : bq[l * 128 + col];
        } else if (col < 256) {
            int cc = col - 128; int h = cc >> 4; int eo = cc & 15;
            float scale = p_rel[l * 8 + h] * 0.25f * 1.4426950408889634f;
            float s = 0.f;
            #pragma unroll
            for (int d = 0; d < 16; ++d) {
                float w = (r < 128) ? Wk_l[r * 128 + h * 16 + d] : bk[l * 128 + h * 16 + d];
                s += w * ar_l[h * 256 + d * 16 + eo];
            }
            val = s * scale;
        } else {
            int cc = col - 256; int h = cc >> 4; int eo = cc & 15;
            float s = 0.f;
            #pragma unroll
            for (int d = 0; d < 16; ++d) {
                float w = (r < 128) ? Wv_l[r * 128 + h * 16 + d] : bv[l * 128 + h * 16 + d];
                s += w * mr_l[h * 256 + d * 16 + eo];
            }
            val = s;
        }
        if (r < 128) BfT[(size_t)l * 49152 + (size_t)col * 128 + r] = f2bf(val);
        else         biasf[l * 384 + col] = val;
    } else if (idx < 2 * 129 * 384 + 2 * 16384) {
        int i = idx - 2 * 129 * 384;
        int l = i >> 14; int j = i & 16383;
        int r = j >> 7, c = j & 127;
        aWT[(size_t)l * 16384 + (size_t)c * 128 + r] = f2bf(aW[(size_t)l * 16384 + r * 128 + c]);
    } else if (idx < 2 * 129 * 384 + 2 * 16384 + 8192) {
        int i = idx - (2 * 129 * 384 + 2 * 16384);
        int c = i >> 7, r = i & 127;
        fcWT[(size_t)c * 128 + r] = f2bf(fcW[(size_t)r * 64 + c]);
    }
}

// ---------------- MFMA bf16 GEMM, 64 rows x Ncols per block ----------------------
// MODE 0 (QKV):  cols 0..127 -> qb; 128..255 -> kb; 256..383 -> vb (all bf16 [NN][128])
// MODE 1 (agg):  gelu on A, epilogue relu(beta*(.)+(1-beta)*Hprev) -> houtB bf16
// MODE 2 (fc):   f32 out via LDS transpose, Ncols=64
// AFMT: 0 = A f32 (Af), 1 = A bf16 (Ab).  HPFMT: Hprev format for MODE 1.
template <int MODE, int AFMT, int HPFMT>
__global__ __launch_bounds__(256) void mfma_gemm_kernel(
    const float* __restrict__ Af, const unsigned short* __restrict__ Ab,
    const unsigned short* __restrict__ BT, const float* __restrict__ bias,
    float* __restrict__ outF, unsigned short* __restrict__ qb,
    unsigned short* __restrict__ kb, unsigned short* __restrict__ vb,
    unsigned short* __restrict__ houtB,
    const float* __restrict__ HprevF, const unsigned short* __restrict__ HprevB,
    const float* __restrict__ skip_p, int Ncols)
{
    __shared__ unsigned short As[64][136];
    __shared__ unsigned short Bs[64][136];   // MODE 2: reused as f32 transpose tile
    int t = threadIdx.x;
    int row0 = blockIdx.x * 64;
    int w = t >> 6;
    int l = t & 63;
    int lr = l & 15;
    int quad = l >> 4;

    // ---- stage A tile (64 x 128) as bf16 ----
    #pragma unroll
    for (int i = 0; i < 4; ++i) {
        int idx = t + i * 256;
        int r = idx >> 4;
        int c8 = (idx & 15) * 8;
        if (AFMT == 0) {
            float4 a0 = *(const float4*)(Af + (size_t)(row0 + r) * 128 + c8);
            float4 a1 = *(const float4*)(Af + (size_t)(row0 + r) * 128 + c8 + 4);
            ushort4 u0, u1;
            u0.x = f2bf(a0.x); u0.y = f2bf(a0.y); u0.z = f2bf(a0.z); u0.w = f2bf(a0.w);
            u1.x = f2bf(a1.x); u1.y = f2bf(a1.y); u1.z = f2bf(a1.z); u1.w = f2bf(a1.w);
            *(ushort4*)(&As[r][c8]) = u0;
            *(ushort4*)(&As[r][c8 + 4]) = u1;
        } else {
            u16x8 u = *(const u16x8*)(Ab + (size_t)(row0 + r) * 128 + c8);
            if (MODE == 1) {
                #pragma unroll
                for (int j = 0; j < 8; ++j) u[j] = f2bf(gelu_tanh(bf2f(u[j])));
            }
            *(u16x8*)(&As[r][c8]) = u;
        }
    }

    float beta = 0.f, omb = 0.f;
    if (MODE == 1) {
        float sv = skip_p[0];
        beta = 1.f / (1.f + expf(-sv));
        omb = 1.f - beta;
    }

    int nct = Ncols >> 6;
    for (int ct = 0; ct < nct; ++ct) {
        __syncthreads();
        #pragma unroll
        for (int i = 0; i < 4; ++i) {
            int idx = t + i * 256;
            int r = idx >> 4;
            int c8 = (idx & 15) * 8;
            *(u16x8*)(&Bs[r][c8]) = *(const u16x8*)(BT + (size_t)(ct * 64 + r) * 128 + c8);
        }
        __syncthreads();

        f32x4 acc[4] = {{0.f,0.f,0.f,0.f},{0.f,0.f,0.f,0.f},
                        {0.f,0.f,0.f,0.f},{0.f,0.f,0.f,0.f}};
        #pragma unroll
        for (int kc = 0; kc < 4; ++kc) {
            short8 af = *(const short8*)(&As[w * 16 + lr][kc * 32 + quad * 8]);
            #pragma unroll
            for (int n4 = 0; n4 < 4; ++n4) {
                short8 bfr = *(const short8*)(&Bs[n4 * 16 + lr][kc * 32 + quad * 8]);
                acc[n4] = __builtin_amdgcn_mfma_f32_16x16x32_bf16(af, bfr, acc[n4], 0, 0, 0);
            }
        }

        if (MODE == 2) {
            // f32 out via LDS transpose (single tile) for vectorized stores
            __syncthreads();
            float* Tf = (float*)&Bs[0][0];     // stride 68 floats
            #pragma unroll
            for (int n4 = 0; n4 < 4; ++n4) {
                float bv = bias[ct * 64 + n4 * 16 + lr];
                #pragma unroll
                for (int rr = 0; rr < 4; ++rr)
                    Tf[(w * 16 + quad * 4 + rr) * 68 + n4 * 16 + lr] = acc[n4][rr] + bv;
            }
            __syncthreads();
            int r = t >> 2;
            int cs = (t & 3) * 16;
            #pragma unroll
            for (int j = 0; j < 4; ++j) {
                float4 v = *(float4*)(&Tf[r * 68 + cs + j * 4]);
                *(float4*)(outF + (size_t)(row0 + r) * 64 + cs + j * 4) = v;
            }
        } else {
            // direct scalar stores (R4 pattern — no extra barriers)
            #pragma unroll
            for (int n4 = 0; n4 < 4; ++n4) {
                int col = ct * 64 + n4 * 16 + lr;
                float bv = bias[col];
                #pragma unroll
                for (int rr = 0; rr < 4; ++rr) {
                    int row = row0 + w * 16 + quad * 4 + rr;
                    float v = acc[n4][rr] + bv;
                    if (MODE == 0) {
                        unsigned short* dst = (col < 128) ? qb : ((col < 256) ? kb : vb);
                        dst[(size_t)row * 128 + (col & 127)] = f2bf(v);
                    } else {
                        float hp = (HPFMT == 0) ? HprevF[(size_t)row * 128 + col]
                                                : bf2f(HprevB[(size_t)row * 128 + col]);
                        v = fmaxf(beta * v + omb * hp, 0.f);
                        houtB[(size_t)row * 128 + col] = f2bf(v);
                    }
                }
            }
        }
    }
}

// ---------------- CSR build (once per call; both layers share structure) ---------

__global__ __launch_bounds__(256) void hist_kernel(
    const int* __restrict__ eidx, int* __restrict__ deg)
{
    int e = blockIdx.x * 256 + threadIdx.x;
    if (e < NE) atomicAdd(&deg[eidx[NE + e]], 1);
}

__global__ __launch_bounds__(256) void scan_blocks_kernel(
    const int* __restrict__ deg, int* __restrict__ offs, int* __restrict__ bsum)
{
    __shared__ int s[256];
    int t = threadIdx.x;
    int i = blockIdx.x * 256 + t;
    int v = (i < NN) ? deg[i] : 0;
    s[t] = v;
    __syncthreads();
    #pragma unroll
    for (int off = 1; off < 256; off <<= 1) {
        int u = (t >= off) ? s[t - off] : 0;
        __syncthreads();
        s[t] += u;
        __syncthreads();
    }
    if (i < NN) offs[i] = s[t] - v;
    if (t == 255) bsum[blockIdx.x] = s[255];
}

__global__ __launch_bounds__(256) void scan_top_kernel(
    const int* __restrict__ bsum, int* __restrict__ boffs)
{
    __shared__ int s[256];
    int t = threadIdx.x;
    int v = (t < NB_SCAN) ? bsum[t] : 0;
    s[t] = v;
    __syncthreads();
    #pragma unroll
    for (int off = 1; off < 256; off <<= 1) {
        int u = (t >= off) ? s[t - off] : 0;
        __syncthreads();
        s[t] += u;
        __syncthreads();
    }
    boffs[t] = s[t] - v;
}

__global__ __launch_bounds__(256) void scan_add_kernel(
    int* __restrict__ offs, const int* __restrict__ boffs, int* __restrict__ cursor)
{
    int i = blockIdx.x * 256 + threadIdx.x;
    if (i < NN) {
        int o = offs[i] + boffs[blockIdx.x];
        offs[i] = o;
        cursor[i] = o;
    }
}

__global__ __launch_bounds__(256) void scatter_kernel(
    const int* __restrict__ eidx, int* __restrict__ cursor, int* __restrict__ srcSorted)
{
    int e = blockIdx.x * 256 + threadIdx.x;
    if (e < NE) {
        int s = eidx[e];
        int d = eidx[NE + e];
        int pos = atomicAdd(&cursor[d], 1);
        srcSorted[pos] = s;
    }
}

// ---------------- Fused per-destination softmax + aggregation --------------------
// One wave per dst. lane = es*8 + h: es = edge slot (8 edges in flight), h = head.
// Each lane computes its head's full 16-dim dot in-register; no per-edge shuffles.
// One 51-shuffle butterfly per node at the end. exp2 (log2e folded into kb).
__global__ __launch_bounds__(256) void aggregate_kernel(
    const unsigned short* __restrict__ qb, const unsigned short* __restrict__ kb,
    const unsigned short* __restrict__ vb,
    const int* __restrict__ deg, const int* __restrict__ offs,
    const int* __restrict__ srcSorted, unsigned short* __restrict__ aggb)
{
    int n = (blockIdx.x * 256 + threadIdx.x) >> 6;
    int lane = threadIdx.x & 63;
    int es = lane >> 3;
    int h = lane & 7;

    float q[16];
    {
        const unsigned short* qp = qb + (size_t)n * 128 + h * 16;
        unpack8(*(const u16x8*)qp, q);
        unpack8(*(const u16x8*)(qp + 8), q + 8);
    }
    float acc[16];
    #pragma unroll
    for (int j = 0; j < 16; ++j) acc[j] = 0.f;
    float den = 0.f;

    int start = offs[n];
    int d = deg[n];
    int ng = (d + 7) >> 3;
    if (d > 0) {
        int lastIdx = start + d - 1;
        int i0 = start + es; if (i0 > lastIdx) i0 = lastIdx;
        int src = srcSorted[i0];
        const unsigned short* kp = kb + (size_t)src * 128 + h * 16;
        const unsigned short* vp = vb + (size_t)src * 128 + h * 16;
        u16x8 k0 = *(const u16x8*)kp,        k1 = *(const u16x8*)(kp + 8);
        u16x8 v0 = *(const u16x8*)vp,        v1 = *(const u16x8*)(vp + 8);
        for (int g = 0; g < ng; ++g) {
            u16x8 nk0 = k0, nk1 = k1, nv0 = v0, nv1 = v1;
            if (g + 1 < ng) {
                int ni = start + (g + 1) * 8 + es; if (ni > lastIdx) ni = lastIdx;
                int srcn = srcSorted[ni];
                const unsigned short* nkp = kb + (size_t)srcn * 128 + h * 16;
                const unsigned short* nvp = vb + (size_t)srcn * 128 + h * 16;
                nk0 = *(const u16x8*)nkp; nk1 = *(const u16x8*)(nkp + 8);
                nv0 = *(const u16x8*)nvp; nv1 = *(const u16x8*)(nvp + 8);
            }
            float kf[16];
            unpack8(k0, kf); unpack8(k1, kf + 8);
            float p = 0.f;
            #pragma unroll
            for (int j = 0; j < 16; ++j) p = fmaf(q[j], kf[j], p);
            float ev = (g * 8 + es < d) ? exp2f(p) : 0.f;
            den += ev;
            float vf[16];
            unpack8(v0, vf); unpack8(v1, vf + 8);
            #pragma unroll
            for (int j = 0; j < 16; ++j) acc[j] = fmaf(vf[j], ev, acc[j]);
            k0 = nk0; k1 = nk1; v0 = nv0; v1 = nv1;
        }
    }
    // butterfly reduce across edge slots (xor 8,16,32)
    #pragma unroll
    for (int m = 8; m < 64; m <<= 1) {
        den += __shfl_xor(den, m, 64);
        #pragma unroll
        for (int j = 0; j < 16; ++j) acc[j] += __shfl_xor(acc[j], m, 64);
    }
    if (es == 0) {
        float w = 1.f / (den + 1e-16f);
        u16x8 o0, o1;
        #pragma unroll
        for (int j = 0; j < 8; ++j) {
            o0[j] = f2bf(acc[j] * w);
            o1[j] = f2bf(acc[j + 8] * w);
        }
        *(u16x8*)(aggb + (size_t)n * 128 + h * 16) = o0;
        *(u16x8*)(aggb + (size_t)n * 128 + h * 16 + 8) = o1;
    }
}

extern "C" void kernel_launch(void* const* d_in, const int* in_sizes, int n_in,
                              void* d_out, int out_size, void* d_ws, size_t ws_size,
                              hipStream_t stream) {
    const float* x     = (const float*)d_in[0];
    const int*   eidx  = (const int*)d_in[1];
    const float* Wk    = (const float*)d_in[2];
    const float* bk    = (const float*)d_in[3];
    const float* Wq    = (const float*)d_in[4];
    const float* bq    = (const float*)d_in[5];
    const float* Wv    = (const float*)d_in[6];
    const float* bv    = (const float*)d_in[7];
    const float* a_rel = (const float*)d_in[8];
    const float* m_rel = (const float*)d_in[9];
    const float* p_rel = (const float*)d_in[10];
    const float* skip  = (const float*)d_in[11];
    const float* aW    = (const float*)d_in[12];
    const float* ab    = (const float*)d_in[13];
    const float* fcW   = (const float*)d_in[14];
    const float* fcb   = (const float*)d_in[15];
    float* out = (float*)d_out;

    float* biasf = (float*)d_ws;                              // 2*384
    unsigned short* hb   = (unsigned short*)(biasf + 768);    // NN*128
    unsigned short* qb   = hb + (size_t)NN * 128;             // NN*128
    unsigned short* kbuf = qb + (size_t)NN * 128;             // NN*128
    unsigned short* vbuf = kbuf + (size_t)NN * 128;           // NN*128
    unsigned short* aggb = vbuf + (size_t)NN * 128;           // NN*128
    unsigned short* BfT  = aggb + (size_t)NN * 128;           // 2*384*128
    unsigned short* aWT  = BfT + 2 * 384 * 128;               // 2*128*128
    unsigned short* fcWT = aWT + 2 * 128 * 128;               // 64*128
    int* deg       = (int*)(fcWT + 64 * 128);                 // NN
    int* offs      = deg + NN;
    int* cursor    = offs + NN;
    int* bsum      = cursor + NN;                             // 256
    int* boffs     = bsum + 256;                              // 256
    int* srcSorted = boffs + 256;                             // NE

    // ---- weight prep (both layers + fc), one launch ----
    weights_kernel<<<547, 256, 0, stream>>>(
        Wq, bq, Wk, bk, a_rel, Wv, bv, m_rel, p_rel, aW, fcW,
        BfT, biasf, aWT, fcWT);

    // ---- CSR build ----
    hipMemsetAsync(deg, 0, (size_t)NN * sizeof(int), stream);
    hist_kernel<<<(NE + 255) / 256, 256, 0, stream>>>(eidx, deg);
    scan_blocks_kernel<<<NB_SCAN, 256, 0, stream>>>(deg, offs, bsum);
    scan_top_kernel<<<1, 256, 0, stream>>>(bsum, boffs);
    scan_add_kernel<<<NB_SCAN, 256, 0, stream>>>(offs, boffs, cursor);
    scatter_kernel<<<(NE + 255) / 256, 256, 0, stream>>>(eidx, cursor, srcSorted);

    // ---- layer 0 ----
    mfma_gemm_kernel<0, 0, 0><<<625, 256, 0, stream>>>(
        x, nullptr, BfT, biasf, nullptr, qb, kbuf, vbuf, nullptr, nullptr, nullptr, nullptr, 384);
    aggregate_kernel<<<NN / 4, 256, 0, stream>>>(qb, kbuf, vbuf, deg, offs, srcSorted, aggb);
    mfma_gemm_kernel<1, 1, 0><<<625, 256, 0, stream>>>(
        nullptr, aggb, aWT, ab, nullptr, nullptr, nullptr, nullptr, hb, x, nullptr, skip, 128);

    // ---- layer 1 ----
    mfma_gemm_kernel<0, 1, 0><<<625, 256, 0, stream>>>(
        nullptr, hb, BfT + 49152, biasf + 384, nullptr, qb, kbuf, vbuf, nullptr, nullptr, nullptr, nullptr, 384);
    aggregate_kernel<<<NN / 4, 256, 0, stream>>>(qb, kbuf, vbuf, deg, offs, srcSorted, aggb);
    mfma_gemm_kernel<1, 1, 1><<<625, 256, 0, stream>>>(
        nullptr, aggb, aWT + 16384, ab + 128, nullptr, nullptr, nullptr, nullptr, hb, nullptr, hb, skip + 1, 128);

    // ---- final fc ----
    mfma_gemm_kernel<2, 1, 0><<<625, 256, 0, stream>>>(
        nullptr, hb, fcWT, fcb, out, nullptr, nullptr, nullptr, nullptr, nullptr, nullptr, nullptr, 64);
}